// Round 2
// baseline (355.045 us; speedup 1.0000x reference)
//
#include <hip/hip_runtime.h>
#include <hip/hip_bf16.h>

typedef __attribute__((ext_vector_type(8))) __bf16 bf16x8;
typedef __attribute__((ext_vector_type(4))) float f32x4;

#define T_SEQ   2048
#define NHEADS  16
#define DK      64
#define BATCH   2
#define DMODEL  1024

__device__ __forceinline__ void gload_lds16(const void* g, void* l) {
  __builtin_amdgcn_global_load_lds((const __attribute__((address_space(1))) void*)g,
                                   (__attribute__((address_space(3))) void*)l, 16, 0, 0);
}

// ---------------- f32 -> bf16 convert (vectorized) ----------------
__global__ __launch_bounds__(256) void f32_to_bf16_k(const float* __restrict__ s,
                                                     __bf16* __restrict__ d, int n) {
  int i = (blockIdx.x * 256 + threadIdx.x) * 8;
  if (i >= n) return;
  float4 a = *(const float4*)(s + i);
  float4 b = *(const float4*)(s + i + 4);
  bf16x8 o;
  o[0] = (__bf16)a.x; o[1] = (__bf16)a.y; o[2] = (__bf16)a.z; o[3] = (__bf16)a.w;
  o[4] = (__bf16)b.x; o[5] = (__bf16)b.y; o[6] = (__bf16)b.z; o[7] = (__bf16)b.w;
  *(bf16x8*)(d + i) = o;
}

// ---------------- generic GEMM: C(M,N) = A(M,K) @ W(N,K)^T ----------------
// 128x128 tile, BK=32, 4 waves (2x2), each wave 64x64 = 4x4 frags of 16x16.
template <typename OutT>
__global__ __launch_bounds__(256) void gemm_bt(const __bf16* __restrict__ A,
                                               const __bf16* __restrict__ W,
                                               OutT* __restrict__ C,
                                               int M, int N, int K) {
  __shared__ alignas(16) __bf16 At[128 * 32];
  __shared__ alignas(16) __bf16 Bt[128 * 32];
  const int tid = threadIdx.x, w = tid >> 6, l = tid & 63;
  const int l16 = l & 15, lq = l >> 4;
  const int wm = w >> 1, wn = w & 1;
  const int br = blockIdx.y * 128, bc = blockIdx.x * 128;
  f32x4 acc[4][4] = {};
  const int off = w * 1024 + l * 16;       // byte offset within a 4KB half-tile
  const int rA = off >> 6, cA = off & 63;  // 64B per row (32 bf16)

  for (int kt = 0; kt < K; kt += 32) {
    __syncthreads();
    gload_lds16((const char*)A + ((size_t)(br + rA) * K + kt) * 2 + cA,
                (char*)At + w * 1024);
    gload_lds16((const char*)A + ((size_t)(br + 64 + rA) * K + kt) * 2 + cA,
                (char*)At + 4096 + w * 1024);
    gload_lds16((const char*)W + ((size_t)(bc + rA) * K + kt) * 2 + cA,
                (char*)Bt + w * 1024);
    gload_lds16((const char*)W + ((size_t)(bc + 64 + rA) * K + kt) * 2 + cA,
                (char*)Bt + 4096 + w * 1024);
    __syncthreads();

    bf16x8 af[4], bfr[4];
#pragma unroll
    for (int m = 0; m < 4; ++m)
      af[m] = *(const bf16x8*)(At + (wm * 64 + m * 16 + l16) * 32 + lq * 8);
#pragma unroll
    for (int n = 0; n < 4; ++n)
      bfr[n] = *(const bf16x8*)(Bt + (wn * 64 + n * 16 + l16) * 32 + lq * 8);
#pragma unroll
    for (int m = 0; m < 4; ++m)
#pragma unroll
      for (int n = 0; n < 4; ++n)
        acc[m][n] = __builtin_amdgcn_mfma_f32_16x16x32_bf16(af[m], bfr[n], acc[m][n], 0, 0, 0);
  }

#pragma unroll
  for (int m = 0; m < 4; ++m)
#pragma unroll
    for (int n = 0; n < 4; ++n)
#pragma unroll
      for (int r = 0; r < 4; ++r) {
        int row = br + wm * 64 + m * 16 + lq * 4 + r;
        int col = bc + wn * 64 + n * 16 + l16;
        float v = acc[m][n][r];
        if constexpr (__is_same(OutT, float))
          C[(size_t)row * N + col] = v;
        else
          C[(size_t)row * N + col] = (__bf16)v;
      }
}

// ---------------- RoPE cos/sin table: tbl[t][j] = (cos, sin) ----------------
__global__ __launch_bounds__(256) void rope_table_k(const int* __restrict__ pos,
                                                    float2* __restrict__ tbl) {
  int idx = blockIdx.x * 256 + threadIdx.x;  // T*32
  int t = idx >> 5, j = idx & 31;
  float p = (float)pos[t];
  float inv = powf(10000.0f, -(float)j * (1.0f / 32.0f));
  float a = p * inv;
  tbl[idx] = make_float2(cosf(a), sinf(a));
}

// ---------------- RoPE apply + transpose: (B,T,H*64) -> (B,H,T,64) ----------
__global__ __launch_bounds__(256) void rope_apply_k(const __bf16* __restrict__ src,
                                                    __bf16* __restrict__ dst,
                                                    const float2* __restrict__ tbl) {
  int idx = blockIdx.x * 256 + threadIdx.x;  // B*T*H, h fastest
  int h = idx & 15; int bt = idx >> 4; int t = bt & (T_SEQ - 1); int b = bt >> 11;
  const __bf16* s = src + (size_t)bt * DMODEL + h * DK;
  __bf16* d = dst + ((size_t)(b * NHEADS + h) * T_SEQ + t) * DK;
  const float2* tb = tbl + t * 32;
#pragma unroll
  for (int c = 0; c < 8; ++c) {
    bf16x8 v = *(const bf16x8*)(s + c * 8);
    bf16x8 o;
#pragma unroll
    for (int p = 0; p < 4; ++p) {
      float e = (float)v[2 * p], od = (float)v[2 * p + 1];
      float2 cs = tb[c * 4 + p];
      o[2 * p]     = (__bf16)(e * cs.x - od * cs.y);
      o[2 * p + 1] = (__bf16)(e * cs.y + od * cs.x);
    }
    *(bf16x8*)(d + c * 8) = o;
  }
}

// ---------------- V transpose: (B,T,H*64) -> (B,H,64,T) ----------------
__global__ __launch_bounds__(256) void v_transpose_k(const __bf16* __restrict__ src,
                                                     __bf16* __restrict__ dst) {
  int bh = blockIdx.x >> 3; int dblk = (blockIdx.x & 7) * 8;
  int b = bh >> 4, h = bh & 15;
  for (int t = threadIdx.x; t < T_SEQ; t += 256) {
    bf16x8 v = *(const bf16x8*)(src + (size_t)(b * T_SEQ + t) * DMODEL + h * DK + dblk);
#pragma unroll
    for (int j = 0; j < 8; ++j)
      dst[(size_t)(bh * DK + dblk + j) * T_SEQ + t] = v[j];
  }
}

// ---------------- flash attention ----------------
// grid (B*H, T/64); 4 waves, each wave owns 16 q rows. K/V tiles of 32 keys in LDS.
__global__ __launch_bounds__(256) void attn_k(const __bf16* __restrict__ Qr,
                                              const __bf16* __restrict__ Kr,
                                              const __bf16* __restrict__ Vt,
                                              const int* __restrict__ pos,
                                              __bf16* __restrict__ out) {
  __shared__ alignas(16) __bf16 Ktile[32 * 64];  // [key][d]
  __shared__ alignas(16) __bf16 Vtile[64 * 32];  // [d][key]
  __shared__ alignas(16) __bf16 Ptile[4][16 * 32];
  const int bh = blockIdx.x; const int b = bh >> 4; const int h = bh & 15;
  const int qb0 = blockIdx.y * 64;
  const int tid = threadIdx.x, w = tid >> 6, l = tid & 63;
  const int l16 = l & 15, lq = l >> 4;

  const __bf16* Qbase = Qr + ((size_t)bh * T_SEQ + qb0 + w * 16) * DK;
  bf16x8 aq0 = *(const bf16x8*)(Qbase + l16 * DK + lq * 8);
  bf16x8 aq1 = *(const bf16x8*)(Qbase + l16 * DK + 32 + lq * 8);

  int posq[4]; float mrow[4], lrow[4]; f32x4 acc[4] = {};
#pragma unroll
  for (int r = 0; r < 4; ++r) {
    posq[r] = pos[qb0 + w * 16 + lq * 4 + r];
    mrow[r] = -1e30f; lrow[r] = 0.0f;
  }

  const int nsteps = qb0 / 32 + 2;
  for (int s32 = 0; s32 < nsteps; ++s32) {
    const int kt = s32 * 32;
    __syncthreads();
    {
      const int off = w * 1024 + l * 16;
      const int krow = off >> 7, kcB = off & 127;   // K: 128B rows
      gload_lds16((const char*)Kr + ((size_t)(bh * T_SEQ + kt + krow) * DK) * 2 + kcB,
                  (char*)Ktile + w * 1024);
      const int vd = off >> 6, vcB = off & 63;      // V^T: 64B row-chunks
      gload_lds16((const char*)Vt + ((size_t)(bh * DK + vd) * T_SEQ + kt) * 2 + vcB,
                  (char*)Vtile + w * 1024);
    }
    __syncthreads();

    // S = Q K^T  (16 q x 32 keys per wave)
    f32x4 s0 = {0.f, 0.f, 0.f, 0.f}, s1 = {0.f, 0.f, 0.f, 0.f};
    bf16x8 bk;
    bk = *(const bf16x8*)(Ktile + l16 * 64 + lq * 8);        s0 = __builtin_amdgcn_mfma_f32_16x16x32_bf16(aq0, bk, s0, 0, 0, 0);
    bk = *(const bf16x8*)(Ktile + l16 * 64 + 32 + lq * 8);   s0 = __builtin_amdgcn_mfma_f32_16x16x32_bf16(aq1, bk, s0, 0, 0, 0);
    bk = *(const bf16x8*)(Ktile + (16 + l16) * 64 + lq * 8);      s1 = __builtin_amdgcn_mfma_f32_16x16x32_bf16(aq0, bk, s1, 0, 0, 0);
    bk = *(const bf16x8*)(Ktile + (16 + l16) * 64 + 32 + lq * 8); s1 = __builtin_amdgcn_mfma_f32_16x16x32_bf16(aq1, bk, s1, 0, 0, 0);

    const int pk0 = pos[kt + l16], pk1 = pos[kt + 16 + l16];
#pragma unroll
    for (int r = 0; r < 4; ++r) {
      float v0 = (pk0 <= posq[r]) ? s0[r] * 0.125f : -1e30f;
      float v1 = (pk1 <= posq[r]) ? s1[r] * 0.125f : -1e30f;
      float m = fmaxf(v0, v1);
      m = fmaxf(m, __shfl_xor(m, 1));
      m = fmaxf(m, __shfl_xor(m, 2));
      m = fmaxf(m, __shfl_xor(m, 4));
      m = fmaxf(m, __shfl_xor(m, 8));
      float mn = fmaxf(mrow[r], m);
      float alpha = __expf(mrow[r] - mn);
      float p0 = (pk0 <= posq[r]) ? __expf(v0 - mn) : 0.0f;
      float p1 = (pk1 <= posq[r]) ? __expf(v1 - mn) : 0.0f;
      float rs = p0 + p1;
      rs += __shfl_xor(rs, 1);
      rs += __shfl_xor(rs, 2);
      rs += __shfl_xor(rs, 4);
      rs += __shfl_xor(rs, 8);
      lrow[r] = lrow[r] * alpha + rs;
      mrow[r] = mn;
#pragma unroll
      for (int t = 0; t < 4; ++t) acc[t][r] *= alpha;
      Ptile[w][(lq * 4 + r) * 32 + l16] = (__bf16)p0;
      Ptile[w][(lq * 4 + r) * 32 + 16 + l16] = (__bf16)p1;
    }

    // PV: A = P (16x32), B = V (32 keys x 64 d) from Vtile[d][key]
    bf16x8 ap = *(const bf16x8*)(&Ptile[w][l16 * 32 + lq * 8]);
#pragma unroll
    for (int t = 0; t < 4; ++t) {
      bf16x8 bv = *(const bf16x8*)(Vtile + (16 * t + l16) * 32 + lq * 8);
      acc[t] = __builtin_amdgcn_mfma_f32_16x16x32_bf16(ap, bv, acc[t], 0, 0, 0);
    }
  }

  // epilogue: out (B,T,H*64) bf16
#pragma unroll
  for (int r = 0; r < 4; ++r) {
    float inv = 1.0f / lrow[r];
    int row = b * T_SEQ + qb0 + w * 16 + lq * 4 + r;
#pragma unroll
    for (int t = 0; t < 4; ++t)
      out[(size_t)row * DMODEL + h * DK + 16 * t + l16] = (__bf16)(acc[t][r] * inv);
  }
}

extern "C" void kernel_launch(void* const* d_in, const int* in_sizes, int n_in,
                              void* d_out, int out_size, void* d_ws, size_t ws_size,
                              hipStream_t stream) {
  const float* x  = (const float*)d_in[0];
  const float* Wq = (const float*)d_in[1];
  const float* Wk = (const float*)d_in[2];
  const float* Wv = (const float*)d_in[3];
  const float* Wo = (const float*)d_in[4];
  const int* pos  = (const int*)d_in[5];

  char* ws = (char*)d_ws;
  __bf16* xb   = (__bf16*)(ws + 0);                 // 8 MB  (4096x1024)
  __bf16* wqb  = (__bf16*)(ws + 8388608);           // 2 MB
  __bf16* wkb  = (__bf16*)(ws + 10485760);          // 2 MB
  __bf16* wvb  = (__bf16*)(ws + 12582912);          // 2 MB
  __bf16* wob  = (__bf16*)(ws + 14680064);          // 2 MB
  __bf16* qtmp = (__bf16*)(ws + 16777216);          // 8 MB (also reused as attn out)
  __bf16* ktmp = (__bf16*)(ws + 25165824);          // 8 MB
  __bf16* vtmp = (__bf16*)(ws + 33554432);          // 8 MB
  __bf16* qr   = (__bf16*)(ws + 41943040);          // 8 MB (B,H,T,64)
  __bf16* kr   = (__bf16*)(ws + 50331648);          // 8 MB (B,H,T,64)
  __bf16* vt   = (__bf16*)(ws + 58720256);          // 8 MB (B,H,64,T)
  float2* tbl  = (float2*)(ws + 67108864);          // 512 KB
  __bf16* ao   = qtmp;                              // attn output reuses qtmp

  const int M = BATCH * T_SEQ;  // 4096

  f32_to_bf16_k<<<2048, 256, 0, stream>>>(x, xb, 4194304);
  f32_to_bf16_k<<<512, 256, 0, stream>>>(Wq, wqb, 1048576);
  f32_to_bf16_k<<<512, 256, 0, stream>>>(Wk, wkb, 1048576);
  f32_to_bf16_k<<<512, 256, 0, stream>>>(Wv, wvb, 1048576);
  f32_to_bf16_k<<<512, 256, 0, stream>>>(Wo, wob, 1048576);

  gemm_bt<__bf16><<<dim3(8, 32), 256, 0, stream>>>(xb, wqb, qtmp, M, DMODEL, DMODEL);
  gemm_bt<__bf16><<<dim3(8, 32), 256, 0, stream>>>(xb, wkb, ktmp, M, DMODEL, DMODEL);
  gemm_bt<__bf16><<<dim3(8, 32), 256, 0, stream>>>(xb, wvb, vtmp, M, DMODEL, DMODEL);

  rope_table_k<<<256, 256, 0, stream>>>(pos, tbl);
  rope_apply_k<<<256, 256, 0, stream>>>(qtmp, qr, tbl);
  rope_apply_k<<<256, 256, 0, stream>>>(ktmp, kr, tbl);
  v_transpose_k<<<256, 256, 0, stream>>>(vtmp, vt);

  attn_k<<<dim3(32, 32), 256, 0, stream>>>(qr, kr, vt, pos, ao);

  gemm_bt<float><<<dim3(8, 32), 256, 0, stream>>>(ao, wob, (float*)d_out, M, DMODEL, DMODEL);
}

// Round 3
// 251.357 us; speedup vs baseline: 1.4125x; 1.4125x over previous
//
#include <hip/hip_runtime.h>
#include <hip/hip_bf16.h>

typedef __attribute__((ext_vector_type(8))) __bf16 bf16x8;
typedef __attribute__((ext_vector_type(4))) float f32x4;

#define T_SEQ   2048
#define DMODEL  1024

__device__ __forceinline__ void gload_lds16(const void* g, void* l) {
  __builtin_amdgcn_global_load_lds((const __attribute__((address_space(1))) void*)g,
                                   (__attribute__((address_space(3))) void*)l, 16, 0, 0);
}
#define VMCNT0() asm volatile("s_waitcnt vmcnt(0)" ::: "memory")

// ---------------- f32 -> bf16 convert (vectorized) ----------------
__global__ __launch_bounds__(256) void f32_to_bf16_k(const float* __restrict__ s,
                                                     __bf16* __restrict__ d, int n) {
  int i = (blockIdx.x * 256 + threadIdx.x) * 8;
  if (i >= n) return;
  float4 a = *(const float4*)(s + i);
  float4 b = *(const float4*)(s + i + 4);
  bf16x8 o;
  o[0] = (__bf16)a.x; o[1] = (__bf16)a.y; o[2] = (__bf16)a.z; o[3] = (__bf16)a.w;
  o[4] = (__bf16)b.x; o[5] = (__bf16)b.y; o[6] = (__bf16)b.z; o[7] = (__bf16)b.w;
  *(bf16x8*)(d + i) = o;
}

// ---------------- RoPE cos/sin table: tbl[t][j] = (cos, sin) ----------------
__global__ __launch_bounds__(256) void rope_table_k(const int* __restrict__ pos,
                                                    float2* __restrict__ tbl) {
  int idx = blockIdx.x * 256 + threadIdx.x;  // T*32
  int t = idx >> 5, j = idx & 31;
  float p = (float)pos[t];
  float inv = powf(10000.0f, -(float)j * (1.0f / 32.0f));
  float a = p * inv;
  tbl[idx] = make_float2(cosf(a), sinf(a));
}

// ---------------- generic GEMM: C(M,N) = A(M,K) @ W(N,K)^T (for Wo) --------
template <typename OutT>
__global__ __launch_bounds__(256) void gemm_bt(const __bf16* __restrict__ A,
                                               const __bf16* __restrict__ W,
                                               OutT* __restrict__ C,
                                               int M, int N, int K) {
  __shared__ alignas(16) __bf16 At[128 * 32];
  __shared__ alignas(16) __bf16 Bt[128 * 32];
  const int tid = threadIdx.x, w = tid >> 6, l = tid & 63;
  const int l16 = l & 15, lq = l >> 4;
  const int wm = w >> 1, wn = w & 1;
  const int br = blockIdx.y * 128, bc = blockIdx.x * 128;
  f32x4 acc[4][4] = {};
  const int off = w * 1024 + l * 16;
  const int rA = off >> 6, cA = off & 63;

  for (int kt = 0; kt < K; kt += 32) {
    __syncthreads();
    gload_lds16((const char*)A + ((size_t)(br + rA) * K + kt) * 2 + cA,
                (char*)At + w * 1024);
    gload_lds16((const char*)A + ((size_t)(br + 64 + rA) * K + kt) * 2 + cA,
                (char*)At + 4096 + w * 1024);
    gload_lds16((const char*)W + ((size_t)(bc + rA) * K + kt) * 2 + cA,
                (char*)Bt + w * 1024);
    gload_lds16((const char*)W + ((size_t)(bc + 64 + rA) * K + kt) * 2 + cA,
                (char*)Bt + 4096 + w * 1024);
    __syncthreads();

    bf16x8 af[4], bfr[4];
#pragma unroll
    for (int m = 0; m < 4; ++m)
      af[m] = *(const bf16x8*)(At + (wm * 64 + m * 16 + l16) * 32 + lq * 8);
#pragma unroll
    for (int n = 0; n < 4; ++n)
      bfr[n] = *(const bf16x8*)(Bt + (wn * 64 + n * 16 + l16) * 32 + lq * 8);
#pragma unroll
    for (int m = 0; m < 4; ++m)
#pragma unroll
      for (int n = 0; n < 4; ++n)
        acc[m][n] = __builtin_amdgcn_mfma_f32_16x16x32_bf16(af[m], bfr[n], acc[m][n], 0, 0, 0);
  }

#pragma unroll
  for (int m = 0; m < 4; ++m)
#pragma unroll
    for (int n = 0; n < 4; ++n)
#pragma unroll
      for (int r = 0; r < 4; ++r) {
        int row = br + wm * 64 + m * 16 + lq * 4 + r;
        int col = bc + wn * 64 + n * 16 + l16;
        float v = acc[m][n][r];
        if constexpr (__is_same(OutT, float))
          C[(size_t)row * N + col] = v;
        else
          C[(size_t)row * N + col] = (__bf16)v;
      }
}

// ---------------- fused QKV GEMM + RoPE + layout epilogue ----------------
// C(4096,3072) = xb @ [Wq;Wk;Wv]^T. sec = col/1024 is block-uniform.
// q,k: rope applied, written (B,H,T,64). v: written (B,H,64,T).
__global__ __launch_bounds__(256) void gemm_qkv_k(const __bf16* __restrict__ A,
                                                  const __bf16* __restrict__ W,
                                                  __bf16* __restrict__ qr,
                                                  __bf16* __restrict__ kr,
                                                  __bf16* __restrict__ vt,
                                                  const float2* __restrict__ tbl) {
  __shared__ alignas(16) __bf16 At[128 * 32];
  __shared__ alignas(16) __bf16 Bt[128 * 32];
  const int K = 1024;
  const int tid = threadIdx.x, w = tid >> 6, l = tid & 63;
  const int l16 = l & 15, lq = l >> 4;
  const int wm = w >> 1, wn = w & 1;
  const int br = blockIdx.y * 128, bc = blockIdx.x * 128;
  f32x4 acc[4][4] = {};
  const int off = w * 1024 + l * 16;
  const int rA = off >> 6, cA = off & 63;

  for (int kt = 0; kt < K; kt += 32) {
    __syncthreads();
    gload_lds16((const char*)A + ((size_t)(br + rA) * K + kt) * 2 + cA,
                (char*)At + w * 1024);
    gload_lds16((const char*)A + ((size_t)(br + 64 + rA) * K + kt) * 2 + cA,
                (char*)At + 4096 + w * 1024);
    gload_lds16((const char*)W + ((size_t)(bc + rA) * K + kt) * 2 + cA,
                (char*)Bt + w * 1024);
    gload_lds16((const char*)W + ((size_t)(bc + 64 + rA) * K + kt) * 2 + cA,
                (char*)Bt + 4096 + w * 1024);
    __syncthreads();

    bf16x8 af[4], bfr[4];
#pragma unroll
    for (int m = 0; m < 4; ++m)
      af[m] = *(const bf16x8*)(At + (wm * 64 + m * 16 + l16) * 32 + lq * 8);
#pragma unroll
    for (int n = 0; n < 4; ++n)
      bfr[n] = *(const bf16x8*)(Bt + (wn * 64 + n * 16 + l16) * 32 + lq * 8);
#pragma unroll
    for (int m = 0; m < 4; ++m)
#pragma unroll
      for (int n = 0; n < 4; ++n)
        acc[m][n] = __builtin_amdgcn_mfma_f32_16x16x32_bf16(af[m], bfr[n], acc[m][n], 0, 0, 0);
  }

  const int sec = bc >> 10;        // 0=q, 1=k, 2=v — uniform per block
  const int cb = bc & 1023;
  if (sec == 2) {
#pragma unroll
    for (int m = 0; m < 4; ++m)
#pragma unroll
      for (int n = 0; n < 4; ++n)
#pragma unroll
        for (int r = 0; r < 4; ++r) {
          int row = br + wm * 64 + m * 16 + lq * 4 + r;
          int col = cb + wn * 64 + n * 16 + l16;
          int b = row >> 11, t = row & 2047, h = col >> 6, d = col & 63;
          vt[((size_t)((b * 16 + h) * 64 + d)) * T_SEQ + t] = (__bf16)acc[m][n][r];
        }
  } else {
    __bf16* dst = (sec == 0) ? qr : kr;
#pragma unroll
    for (int m = 0; m < 4; ++m)
#pragma unroll
      for (int n = 0; n < 4; ++n)
#pragma unroll
        for (int r = 0; r < 4; ++r) {
          float v = acc[m][n][r];
          float p = __shfl_xor(v, 1);   // even<->odd pair (d^1)
          int row = br + wm * 64 + m * 16 + lq * 4 + r;
          int col = cb + wn * 64 + n * 16 + l16;
          int b = row >> 11, t = row & 2047, h = col >> 6, d = col & 63;
          float2 cs = tbl[t * 32 + (d >> 1)];
          float o = v * cs.x + ((d & 1) ? p * cs.y : -(p * cs.y));
          dst[((size_t)((b * 16 + h) * T_SEQ + t)) * 64 + d] = (__bf16)o;
        }
  }
}

// ---------------- flash attention ----------------
// grid (B*H=32, T/64=32); 4 waves, wave owns 16 q rows. 64-key double-buffered
// tiles, XOR-swizzled K/V/P LDS, 2-phase prefetch with raw barrier.
__global__ __launch_bounds__(256) void attn_k(const __bf16* __restrict__ Qr,
                                              const __bf16* __restrict__ Kr,
                                              const __bf16* __restrict__ Vt,
                                              __bf16* __restrict__ out) {
  __shared__ alignas(16) __bf16 Kt[2][64 * 64];   // [key][d] rows 128B, swizzled
  __shared__ alignas(16) __bf16 Vtl[2][64 * 64];  // [d][key] rows 128B, swizzled
  __shared__ alignas(16) __bf16 Pt[4][16 * 64];   // per-wave P, rows 128B, swizzled
  const int bh = blockIdx.x, qb0 = blockIdx.y * 64;
  const int tid = threadIdx.x, w = tid >> 6, l = tid & 63;
  const int l16 = l & 15, lq = l >> 4;

  const __bf16* Qbase = Qr + ((size_t)bh * T_SEQ + qb0 + w * 16) * 64;
  bf16x8 aq0 = *(const bf16x8*)(Qbase + l16 * 64 + lq * 8);
  bf16x8 aq1 = *(const bf16x8*)(Qbase + l16 * 64 + 32 + lq * 8);

  float mrow[4], lrow[4]; f32x4 acc[4] = {};
#pragma unroll
  for (int r = 0; r < 4; ++r) { mrow[r] = -1e30f; lrow[r] = 0.0f; }

  const int nt = qb0 / 64 + 1;
  const int offbase = w * 1024 + l * 16;

  auto stage = [&](int bufi, int kt) {
#pragma unroll
    for (int c2 = 0; c2 < 2; ++c2) {
      int o = offbase + c2 * 4096;
      int row = o >> 7, cbyte = o & 127;
      int sw = cbyte ^ ((row & 7) << 4);   // pre-swizzled global source
      gload_lds16((const char*)Kr + ((size_t)(bh * T_SEQ + kt + row) * 64) * 2 + sw,
                  (char*)(&Kt[bufi][0]) + w * 1024 + c2 * 4096);
      gload_lds16((const char*)Vt + ((size_t)(bh * 64 + row) * T_SEQ + kt) * 2 + sw,
                  (char*)(&Vtl[bufi][0]) + w * 1024 + c2 * 4096);
    }
  };

  stage(0, 0);
  VMCNT0();
  __builtin_amdgcn_s_barrier();

  int buf = 0;
  for (int t = 0; t < nt; ++t) {
    const int kt = t * 64;
    if (t + 1 < nt) stage(buf ^ 1, kt + 64);   // prefetch overlaps compute

    const char* K0 = (const char*)&Kt[buf][0];
    const char* V0 = (const char*)&Vtl[buf][0];

    // S = Q K^T : 16 q x 64 keys per wave
    f32x4 s[4] = {};
#pragma unroll
    for (int g = 0; g < 4; ++g) {
      int row = g * 16 + l16;
      int x = (row & 7) << 4;
      bf16x8 b0 = *(const bf16x8*)(K0 + row * 128 + ((lq * 16) ^ x));
      s[g] = __builtin_amdgcn_mfma_f32_16x16x32_bf16(aq0, b0, s[g], 0, 0, 0);
      bf16x8 b1 = *(const bf16x8*)(K0 + row * 128 + ((lq * 16 + 64) ^ x));
      s[g] = __builtin_amdgcn_mfma_f32_16x16x32_bf16(aq1, b1, s[g], 0, 0, 0);
    }

    const bool diag = (t == nt - 1);
    const int qrow_base = qb0 + w * 16;
#pragma unroll
    for (int r = 0; r < 4; ++r) {
      int q = qrow_base + lq * 4 + r;
      float v0 = s[0][r] * 0.125f, v1 = s[1][r] * 0.125f;
      float v2 = s[2][r] * 0.125f, v3 = s[3][r] * 0.125f;
      if (diag) {
        if (kt + l16 > q)      v0 = -1e30f;
        if (kt + 16 + l16 > q) v1 = -1e30f;
        if (kt + 32 + l16 > q) v2 = -1e30f;
        if (kt + 48 + l16 > q) v3 = -1e30f;
      }
      float m = fmaxf(fmaxf(v0, v1), fmaxf(v2, v3));
      m = fmaxf(m, __shfl_xor(m, 1));
      m = fmaxf(m, __shfl_xor(m, 2));
      m = fmaxf(m, __shfl_xor(m, 4));
      m = fmaxf(m, __shfl_xor(m, 8));
      float mn = fmaxf(mrow[r], m);
      float alpha = __expf(mrow[r] - mn);
      float p0 = __expf(v0 - mn), p1 = __expf(v1 - mn);
      float p2 = __expf(v2 - mn), p3 = __expf(v3 - mn);
      float rs = (p0 + p1) + (p2 + p3);
      rs += __shfl_xor(rs, 1);
      rs += __shfl_xor(rs, 2);
      rs += __shfl_xor(rs, 4);
      rs += __shfl_xor(rs, 8);
      lrow[r] = lrow[r] * alpha + rs;
      mrow[r] = mn;
#pragma unroll
      for (int dt = 0; dt < 4; ++dt) acc[dt][r] *= alpha;
      int prow = lq * 4 + r;
      int px = (prow & 7) << 4;
      char* Pw = (char*)&Pt[w][0] + prow * 128;
      *(__bf16*)(Pw + ((l16 * 2) ^ px))      = (__bf16)p0;
      *(__bf16*)(Pw + ((32 + l16 * 2) ^ px)) = (__bf16)p1;
      *(__bf16*)(Pw + ((64 + l16 * 2) ^ px)) = (__bf16)p2;
      *(__bf16*)(Pw + ((96 + l16 * 2) ^ px)) = (__bf16)p3;
    }

    // PV: A = P (16x64), B = V (64 keys x 64 d) from swizzled Vtl[d][key]
#pragma unroll
    for (int ks = 0; ks < 2; ++ks) {
      bf16x8 ap = *(const bf16x8*)((const char*)&Pt[w][0] + l16 * 128 +
                                   ((ks * 64 + lq * 16) ^ ((l16 & 7) << 4)));
#pragma unroll
      for (int dt = 0; dt < 4; ++dt) {
        int row = dt * 16 + l16;
        bf16x8 bv = *(const bf16x8*)(V0 + row * 128 +
                                     ((ks * 64 + lq * 16) ^ ((row & 7) << 4)));
        acc[dt] = __builtin_amdgcn_mfma_f32_16x16x32_bf16(ap, bv, acc[dt], 0, 0, 0);
      }
    }

    VMCNT0();
    __builtin_amdgcn_s_barrier();
    buf ^= 1;
  }

  // epilogue: out (B,T,H*64) bf16
  const int b = bh >> 4, h = bh & 15;
#pragma unroll
  for (int r = 0; r < 4; ++r) {
    float inv = 1.0f / lrow[r];
    size_t row = (size_t)b * T_SEQ + qb0 + w * 16 + lq * 4 + r;
#pragma unroll
    for (int dt = 0; dt < 4; ++dt)
      out[row * DMODEL + h * 64 + dt * 16 + l16] = (__bf16)(acc[dt][r] * inv);
  }
}

extern "C" void kernel_launch(void* const* d_in, const int* in_sizes, int n_in,
                              void* d_out, int out_size, void* d_ws, size_t ws_size,
                              hipStream_t stream) {
  const float* x  = (const float*)d_in[0];
  const float* Wq = (const float*)d_in[1];
  const float* Wk = (const float*)d_in[2];
  const float* Wv = (const float*)d_in[3];
  const float* Wo = (const float*)d_in[4];
  const int* pos  = (const int*)d_in[5];

  char* ws = (char*)d_ws;
  __bf16* xb   = (__bf16*)(ws + 0);                // 8 MB (4096x1024)
  __bf16* wqkv = (__bf16*)(ws + (8u << 20));       // 6 MB (3072x1024)
  __bf16* wob  = (__bf16*)(ws + (14u << 20));      // 2 MB
  __bf16* qr   = (__bf16*)(ws + (16u << 20));      // 8 MB (B,H,T,64)
  __bf16* kr   = (__bf16*)(ws + (24u << 20));      // 8 MB (B,H,T,64)
  __bf16* vt   = (__bf16*)(ws + (32u << 20));      // 8 MB (B,H,64,T)
  __bf16* ao   = (__bf16*)(ws + (40u << 20));      // 8 MB (B,T,1024)
  float2* tbl  = (float2*)(ws + (48u << 20));      // 512 KB

  f32_to_bf16_k<<<2048, 256, 0, stream>>>(x, xb, 4194304);
  f32_to_bf16_k<<<512, 256, 0, stream>>>(Wq, wqkv, 1048576);
  f32_to_bf16_k<<<512, 256, 0, stream>>>(Wk, wqkv + 1048576, 1048576);
  f32_to_bf16_k<<<512, 256, 0, stream>>>(Wv, wqkv + 2097152, 1048576);
  f32_to_bf16_k<<<512, 256, 0, stream>>>(Wo, wob, 1048576);

  rope_table_k<<<256, 256, 0, stream>>>(pos, tbl);

  gemm_qkv_k<<<dim3(24, 32), 256, 0, stream>>>(xb, wqkv, qr, kr, vt, tbl);

  attn_k<<<dim3(32, 32), 256, 0, stream>>>(qr, kr, vt, ao);

  gemm_bt<float><<<dim3(8, 32), 256, 0, stream>>>(ao, wob, (float*)d_out, 4096, DMODEL, DMODEL);
}

// Round 4
// 218.299 us; speedup vs baseline: 1.6264x; 1.1514x over previous
//
#include <hip/hip_runtime.h>
#include <hip/hip_bf16.h>

typedef __attribute__((ext_vector_type(8))) __bf16 bf16x8;
typedef __attribute__((ext_vector_type(4))) __bf16 bf16x4;
typedef __attribute__((ext_vector_type(4))) float f32x4;

#define T_SEQ   2048
#define DMODEL  1024

__device__ __forceinline__ void gload_lds16(const void* g, void* l) {
  __builtin_amdgcn_global_load_lds((const __attribute__((address_space(1))) void*)g,
                                   (__attribute__((address_space(3))) void*)l, 16, 0, 0);
}
#define VMCNT0() asm volatile("s_waitcnt vmcnt(0)" ::: "memory")

// ---------------- f32 -> bf16 convert (vectorized) ----------------
__global__ __launch_bounds__(256) void f32_to_bf16_k(const float* __restrict__ s,
                                                     __bf16* __restrict__ d, int n) {
  int i = (blockIdx.x * 256 + threadIdx.x) * 8;
  if (i >= n) return;
  float4 a = *(const float4*)(s + i);
  float4 b = *(const float4*)(s + i + 4);
  bf16x8 o;
  o[0] = (__bf16)a.x; o[1] = (__bf16)a.y; o[2] = (__bf16)a.z; o[3] = (__bf16)a.w;
  o[4] = (__bf16)b.x; o[5] = (__bf16)b.y; o[6] = (__bf16)b.z; o[7] = (__bf16)b.w;
  *(bf16x8*)(d + i) = o;
}

// fused weight converts: Wq,Wk,Wv -> wqkv (3M), Wo -> wob (1M)
__global__ __launch_bounds__(256) void w_to_bf16_k(const float* __restrict__ Wq,
                                                   const float* __restrict__ Wk,
                                                   const float* __restrict__ Wv,
                                                   const float* __restrict__ Wo,
                                                   __bf16* __restrict__ wqkv,
                                                   __bf16* __restrict__ wob) {
  int i = (blockIdx.x * 256 + threadIdx.x) * 8;   // 0..4M
  int sec = i >> 20, o = i & 1048575;
  const float* s = (sec == 0) ? Wq : (sec == 1) ? Wk : (sec == 2) ? Wv : Wo;
  __bf16* d = (sec == 3) ? (wob + o) : (wqkv + i);
  float4 a = *(const float4*)(s + o);
  float4 b = *(const float4*)(s + o + 4);
  bf16x8 v;
  v[0] = (__bf16)a.x; v[1] = (__bf16)a.y; v[2] = (__bf16)a.z; v[3] = (__bf16)a.w;
  v[4] = (__bf16)b.x; v[5] = (__bf16)b.y; v[6] = (__bf16)b.z; v[7] = (__bf16)b.w;
  *(bf16x8*)d = v;
}

// ---------------- RoPE cos/sin table: tbl[t][j] = (cos, sin) ----------------
__global__ __launch_bounds__(256) void rope_table_k(const int* __restrict__ pos,
                                                    float2* __restrict__ tbl) {
  int idx = blockIdx.x * 256 + threadIdx.x;  // T*32
  int t = idx >> 5, j = idx & 31;
  float p = (float)pos[t];
  float inv = powf(10000.0f, -(float)j * (1.0f / 32.0f));
  float a = p * inv;
  tbl[idx] = make_float2(cosf(a), sinf(a));
}

// ---------------- generic GEMM: C(M,N) = A(M,K) @ W(N,K)^T (for Wo) --------
template <typename OutT>
__global__ __launch_bounds__(256) void gemm_bt(const __bf16* __restrict__ A,
                                               const __bf16* __restrict__ W,
                                               OutT* __restrict__ C,
                                               int M, int N, int K) {
  __shared__ alignas(16) __bf16 At[128 * 32];
  __shared__ alignas(16) __bf16 Bt[128 * 32];
  const int tid = threadIdx.x, w = tid >> 6, l = tid & 63;
  const int l16 = l & 15, lq = l >> 4;
  const int wm = w >> 1, wn = w & 1;
  const int br = blockIdx.y * 128, bc = blockIdx.x * 128;
  f32x4 acc[4][4] = {};
  const int off = w * 1024 + l * 16;
  const int rA = off >> 6, cA = off & 63;

  for (int kt = 0; kt < K; kt += 32) {
    __syncthreads();
    gload_lds16((const char*)A + ((size_t)(br + rA) * K + kt) * 2 + cA,
                (char*)At + w * 1024);
    gload_lds16((const char*)A + ((size_t)(br + 64 + rA) * K + kt) * 2 + cA,
                (char*)At + 4096 + w * 1024);
    gload_lds16((const char*)W + ((size_t)(bc + rA) * K + kt) * 2 + cA,
                (char*)Bt + w * 1024);
    gload_lds16((const char*)W + ((size_t)(bc + 64 + rA) * K + kt) * 2 + cA,
                (char*)Bt + 4096 + w * 1024);
    __syncthreads();

    bf16x8 af[4], bfr[4];
#pragma unroll
    for (int m = 0; m < 4; ++m)
      af[m] = *(const bf16x8*)(At + (wm * 64 + m * 16 + l16) * 32 + lq * 8);
#pragma unroll
    for (int n = 0; n < 4; ++n)
      bfr[n] = *(const bf16x8*)(Bt + (wn * 64 + n * 16 + l16) * 32 + lq * 8);
#pragma unroll
    for (int m = 0; m < 4; ++m)
#pragma unroll
      for (int n = 0; n < 4; ++n)
        acc[m][n] = __builtin_amdgcn_mfma_f32_16x16x32_bf16(af[m], bfr[n], acc[m][n], 0, 0, 0);
  }

#pragma unroll
  for (int m = 0; m < 4; ++m)
#pragma unroll
    for (int n = 0; n < 4; ++n)
#pragma unroll
      for (int r = 0; r < 4; ++r) {
        int row = br + wm * 64 + m * 16 + lq * 4 + r;
        int col = bc + wn * 64 + n * 16 + l16;
        float v = acc[m][n][r];
        if constexpr (__is_same(OutT, float))
          C[(size_t)row * N + col] = v;
        else
          C[(size_t)row * N + col] = (__bf16)v;
      }
}

// ---------------- fused QKV GEMM (operand-swapped) + RoPE epilogue ----------
// C^T computed: lane holds 4 consecutive output-cols (d) for one row (t).
// q (scaled by 1/8) and k: rope in-lane, packed 8B stores to (B,H,T,64).
// v: written (B,H,64,T) with 16-lane-coalesced t runs.
__global__ __launch_bounds__(256) void gemm_qkv_k(const __bf16* __restrict__ A,
                                                  const __bf16* __restrict__ W,
                                                  __bf16* __restrict__ qr,
                                                  __bf16* __restrict__ kr,
                                                  __bf16* __restrict__ vt,
                                                  const float2* __restrict__ tbl) {
  __shared__ alignas(16) __bf16 At[128 * 32];
  __shared__ alignas(16) __bf16 Bt[128 * 32];
  const int K = 1024;
  const int tid = threadIdx.x, w = tid >> 6, l = tid & 63;
  const int l16 = l & 15, lq = l >> 4;
  const int wm = w >> 1, wn = w & 1;
  const int br = blockIdx.y * 128, bc = blockIdx.x * 128;
  f32x4 acc[4][4] = {};   // acc[n][m]
  const int off = w * 1024 + l * 16;
  const int rA = off >> 6, cA = off & 63;

  for (int kt = 0; kt < K; kt += 32) {
    __syncthreads();
    gload_lds16((const char*)A + ((size_t)(br + rA) * K + kt) * 2 + cA,
                (char*)At + w * 1024);
    gload_lds16((const char*)A + ((size_t)(br + 64 + rA) * K + kt) * 2 + cA,
                (char*)At + 4096 + w * 1024);
    gload_lds16((const char*)W + ((size_t)(bc + rA) * K + kt) * 2 + cA,
                (char*)Bt + w * 1024);
    gload_lds16((const char*)W + ((size_t)(bc + 64 + rA) * K + kt) * 2 + cA,
                (char*)Bt + 4096 + w * 1024);
    __syncthreads();

    bf16x8 af[4], bfr[4];
#pragma unroll
    for (int m = 0; m < 4; ++m)
      af[m] = *(const bf16x8*)(At + (wm * 64 + m * 16 + l16) * 32 + lq * 8);
#pragma unroll
    for (int n = 0; n < 4; ++n)
      bfr[n] = *(const bf16x8*)(Bt + (wn * 64 + n * 16 + l16) * 32 + lq * 8);
#pragma unroll
    for (int n = 0; n < 4; ++n)
#pragma unroll
      for (int m = 0; m < 4; ++m)
        acc[n][m] = __builtin_amdgcn_mfma_f32_16x16x32_bf16(bfr[n], af[m], acc[n][m], 0, 0, 0);
  }

  const int sec = bc >> 10;        // 0=q, 1=k, 2=v — uniform per block
  const int cb = bc & 1023;
  if (sec == 2) {
#pragma unroll
    for (int n = 0; n < 4; ++n)
#pragma unroll
      for (int m = 0; m < 4; ++m) {
        int d0 = cb + wn * 64 + n * 16 + lq * 4;
        int h = d0 >> 6, dk = d0 & 63;
        int t = br + wm * 64 + m * 16 + l16;
        int b = t >> 11, tt = t & 2047;
#pragma unroll
        for (int r = 0; r < 4; ++r)
          vt[((size_t)((b * 16 + h) * 64 + dk + r)) * T_SEQ + tt] = (__bf16)acc[n][m][r];
      }
  } else {
    __bf16* dst = (sec == 0) ? qr : kr;
    const float sc = (sec == 0) ? 0.125f : 1.0f;   // fold 1/sqrt(64) into Q
#pragma unroll
    for (int n = 0; n < 4; ++n)
#pragma unroll
      for (int m = 0; m < 4; ++m) {
        int d0 = cb + wn * 64 + n * 16 + lq * 4;
        int h = d0 >> 6, dk = d0 & 63;
        int t = br + wm * 64 + m * 16 + l16;
        int b = t >> 11, tt = t & 2047;
        float2 cs0 = tbl[tt * 32 + (dk >> 1)];
        float2 cs1 = tbl[tt * 32 + (dk >> 1) + 1];
        float v0 = acc[n][m][0], v1 = acc[n][m][1];
        float v2 = acc[n][m][2], v3 = acc[n][m][3];
        bf16x4 pk;
        pk[0] = (__bf16)((v0 * cs0.x - v1 * cs0.y) * sc);
        pk[1] = (__bf16)((v0 * cs0.y + v1 * cs0.x) * sc);
        pk[2] = (__bf16)((v2 * cs1.x - v3 * cs1.y) * sc);
        pk[3] = (__bf16)((v2 * cs1.y + v3 * cs1.x) * sc);
        *(bf16x4*)(dst + ((size_t)((b * 16 + h) * T_SEQ + tt)) * 64 + dk) = pk;
      }
  }
}

// ---------------- flash attention (swapped operands) ----------------
// grid (B*H=32, T/64=32); 4 waves, wave owns 16 q rows (q = lane&15).
// S^T = mfma(K, Q): lane holds 16 S-values for ONE q row -> in-lane softmax.
// O^T = mfma(V^T, P^T). 64-key double-buffered swizzled tiles, defer-max.
__global__ __launch_bounds__(256) void attn_k(const __bf16* __restrict__ Qr,
                                              const __bf16* __restrict__ Kr,
                                              const __bf16* __restrict__ Vt,
                                              __bf16* __restrict__ out) {
  __shared__ alignas(16) __bf16 Kt[2][64 * 64];   // [key][d] rows 128B, swizzled
  __shared__ alignas(16) __bf16 Vtl[2][64 * 64];  // [d][key] rows 128B, swizzled
  __shared__ alignas(16) __bf16 Pt[4][16 * 64];   // per-wave P[q][key], swizzled
  const int bh = blockIdx.x, qb0 = blockIdx.y * 64;
  const int tid = threadIdx.x, w = tid >> 6, l = tid & 63;
  const int l16 = l & 15, lq = l >> 4;
  const int px = (l16 & 7) << 4;

  // Q as B-operand: lane holds Q[q=l16][d=lq*8..+7] (+32 for second half)
  const __bf16* Qbase = Qr + ((size_t)bh * T_SEQ + qb0 + w * 16) * 64;
  bf16x8 aq0 = *(const bf16x8*)(Qbase + l16 * 64 + lq * 8);
  bf16x8 aq1 = *(const bf16x8*)(Qbase + l16 * 64 + 32 + lq * 8);

  float mrow = -1e30f, lrow = 0.0f;
  f32x4 acc[4] = {};   // acc[dt]: O^T[d=dt*16+lq*4+r][q=l16]

  const int nt = qb0 / 64 + 1;
  const int offbase = w * 1024 + l * 16;

  auto stage = [&](int bufi, int kt) {
#pragma unroll
    for (int c2 = 0; c2 < 2; ++c2) {
      int o = offbase + c2 * 4096;
      int row = o >> 7, cbyte = o & 127;
      int sw = cbyte ^ ((row & 7) << 4);   // pre-swizzled global source
      gload_lds16((const char*)Kr + ((size_t)(bh * T_SEQ + kt + row) * 64) * 2 + sw,
                  (char*)(&Kt[bufi][0]) + w * 1024 + c2 * 4096);
      gload_lds16((const char*)Vt + ((size_t)(bh * 64 + row) * T_SEQ + kt) * 2 + sw,
                  (char*)(&Vtl[bufi][0]) + w * 1024 + c2 * 4096);
    }
  };

  stage(0, 0);
  VMCNT0();
  __builtin_amdgcn_s_barrier();

  int buf = 0;
  for (int t = 0; t < nt; ++t) {
    const int kt = t * 64;
    if (t + 1 < nt) stage(buf ^ 1, kt + 64);   // prefetch overlaps compute

    const char* K0 = (const char*)&Kt[buf][0];
    const char* V0 = (const char*)&Vtl[buf][0];

    // S^T = K x Q^T : lane gets S[key=16g+lq*4+r][q=l16]
    f32x4 s[4] = {};
    __builtin_amdgcn_s_setprio(1);
#pragma unroll
    for (int g = 0; g < 4; ++g) {
      int row = g * 16 + l16;
      int x = (row & 7) << 4;
      bf16x8 k0 = *(const bf16x8*)(K0 + row * 128 + ((lq * 16) ^ x));
      s[g] = __builtin_amdgcn_mfma_f32_16x16x32_bf16(k0, aq0, s[g], 0, 0, 0);
      bf16x8 k1 = *(const bf16x8*)(K0 + row * 128 + ((lq * 16 + 64) ^ x));
      s[g] = __builtin_amdgcn_mfma_f32_16x16x32_bf16(k1, aq1, s[g], 0, 0, 0);
    }
    __builtin_amdgcn_s_setprio(0);

    if (t == nt - 1) {   // causal mask, diagonal tile only
      int q = qb0 + w * 16 + l16;
#pragma unroll
      for (int g = 0; g < 4; ++g)
#pragma unroll
        for (int r = 0; r < 4; ++r)
          if (kt + g * 16 + lq * 4 + r > q) s[g][r] = -1e30f;
    }

    float pm = -1e30f;
#pragma unroll
    for (int g = 0; g < 4; ++g)
#pragma unroll
      for (int r = 0; r < 4; ++r) pm = fmaxf(pm, s[g][r]);
    pm = fmaxf(pm, __shfl_xor(pm, 16));
    pm = fmaxf(pm, __shfl_xor(pm, 32));

    if (__any(pm > mrow + 8.0f)) {   // defer-max (T13)
      float mn = fmaxf(mrow, pm);
      float alpha = __expf(mrow - mn);
#pragma unroll
      for (int dt = 0; dt < 4; ++dt)
#pragma unroll
        for (int r = 0; r < 4; ++r) acc[dt][r] *= alpha;
      lrow *= alpha;
      mrow = mn;
    }

    char* Pw = (char*)&Pt[w][0] + l16 * 128;
    float rs = 0.0f;
#pragma unroll
    for (int g = 0; g < 4; ++g) {
      bf16x4 pk;
#pragma unroll
      for (int r = 0; r < 4; ++r) {
        float p = __expf(s[g][r] - mrow);
        rs += p;
        pk[r] = (__bf16)p;
      }
      *(bf16x4*)(Pw + ((g * 32 + lq * 8) ^ px)) = pk;
    }
    rs += __shfl_xor(rs, 16);
    rs += __shfl_xor(rs, 32);
    lrow += rs;

    // O^T += V^T x P^T
    __builtin_amdgcn_s_setprio(1);
#pragma unroll
    for (int ks = 0; ks < 2; ++ks) {
      bf16x8 ap = *(const bf16x8*)((const char*)&Pt[w][0] + l16 * 128 +
                                   ((ks * 64 + lq * 16) ^ px));
#pragma unroll
      for (int dt = 0; dt < 4; ++dt) {
        int vrow = dt * 16 + l16;
        bf16x8 vf = *(const bf16x8*)(V0 + vrow * 128 +
                                     ((ks * 64 + lq * 16) ^ ((vrow & 7) << 4)));
        acc[dt] = __builtin_amdgcn_mfma_f32_16x16x32_bf16(vf, ap, acc[dt], 0, 0, 0);
      }
    }
    __builtin_amdgcn_s_setprio(0);

    VMCNT0();
    __builtin_amdgcn_s_barrier();
    buf ^= 1;
  }

  // epilogue: out (B,T,H*64), lane holds 4 consecutive d per dt -> 8B stores
  const int b = bh >> 4, h = bh & 15;
  float inv = 1.0f / lrow;
  size_t row = (size_t)b * T_SEQ + qb0 + w * 16 + l16;
#pragma unroll
  for (int dt = 0; dt < 4; ++dt) {
    bf16x4 o;
#pragma unroll
    for (int r = 0; r < 4; ++r) o[r] = (__bf16)(acc[dt][r] * inv);
    *(bf16x4*)(out + row * DMODEL + h * 64 + dt * 16 + lq * 4) = o;
  }
}

extern "C" void kernel_launch(void* const* d_in, const int* in_sizes, int n_in,
                              void* d_out, int out_size, void* d_ws, size_t ws_size,
                              hipStream_t stream) {
  const float* x  = (const float*)d_in[0];
  const float* Wq = (const float*)d_in[1];
  const float* Wk = (const float*)d_in[2];
  const float* Wv = (const float*)d_in[3];
  const float* Wo = (const float*)d_in[4];
  const int* pos  = (const int*)d_in[5];

  char* ws = (char*)d_ws;
  __bf16* xb   = (__bf16*)(ws + 0);                // 8 MB (4096x1024)
  __bf16* wqkv = (__bf16*)(ws + (8u << 20));       // 6 MB (3072x1024)
  __bf16* wob  = (__bf16*)(ws + (14u << 20));      // 2 MB
  __bf16* qr   = (__bf16*)(ws + (16u << 20));      // 8 MB (B,H,T,64), pre-scaled 1/8
  __bf16* kr   = (__bf16*)(ws + (24u << 20));      // 8 MB (B,H,T,64)
  __bf16* vt   = (__bf16*)(ws + (32u << 20));      // 8 MB (B,H,64,T)
  __bf16* ao   = (__bf16*)(ws + (40u << 20));      // 8 MB (B,T,1024)
  float2* tbl  = (float2*)(ws + (48u << 20));      // 512 KB

  f32_to_bf16_k<<<2048, 256, 0, stream>>>(x, xb, 4194304);
  w_to_bf16_k<<<2048, 256, 0, stream>>>(Wq, Wk, Wv, Wo, wqkv, wob);
  rope_table_k<<<256, 256, 0, stream>>>(pos, tbl);

  gemm_qkv_k<<<dim3(24, 32), 256, 0, stream>>>(xb, wqkv, qr, kr, vt, tbl);

  attn_k<<<dim3(32, 32), 256, 0, stream>>>(qr, kr, vt, ao);

  gemm_bt<float><<<dim3(8, 32), 256, 0, stream>>>(ao, wob, (float*)d_out, 4096, DMODEL, DMODEL);
}